// Round 5
// baseline (253.168 us; speedup 1.0000x reference)
//
#include <hip/hip_runtime.h>
#include <hip/hip_bf16.h>

// ---------------------------------------------------------------------------
// SlidingWindowAttention: fused QKV projection (bf16 MFMA GEMM, m97-style
// global_load_lds staging) + windowed flash attention (bf16 MFMA, S^T trick).
// Q,K stored head-major [b][h][s][d]; V stored transposed [b][h][d][s] so
// every attention global load is cache-line-exact. fp32 output.
// GEMM: grid=768, 2 tiles/block (same m0, adjacent n0) -> no dispatch tail.
// B=4, S=2048, D=1024, H=16, hd=64, WINDOW=128.
// ---------------------------------------------------------------------------

#define NB 4
#define SQ 2048
#define NH 16
#define HD 64
#define DM 1024
#define WIN 128

typedef unsigned short u16;
typedef __bf16 bf16x8 __attribute__((ext_vector_type(8)));
typedef unsigned short us8 __attribute__((ext_vector_type(8)));
typedef unsigned short us4v __attribute__((ext_vector_type(4)));
typedef float f32x4 __attribute__((ext_vector_type(4)));

__device__ __forceinline__ u16 f2b(float f) {
  union { float f; unsigned u; } v; v.f = f;
  unsigned r = v.u + 0x7FFFu + ((v.u >> 16) & 1u);   // RNE
  return (u16)(r >> 16);
}

__device__ __forceinline__ bf16x8 as_bf(us8 v) {
  union { us8 a; bf16x8 b; } u; u.a = v; return u.b;
}

__device__ __forceinline__ f32x4 mfma16(bf16x8 a, bf16x8 b, f32x4 c) {
  return __builtin_amdgcn_mfma_f32_16x16x32_bf16(a, b, c, 0, 0, 0);
}

// async global->LDS, 16B per lane; LDS dest is wave-uniform base + lane*16
__device__ __forceinline__ void gl_lds16(const u16* g, u16* l) {
#if __has_builtin(__builtin_amdgcn_global_load_lds)
  __builtin_amdgcn_global_load_lds(
      (const __attribute__((address_space(1))) void*)g,
      (__attribute__((address_space(3))) void*)l, 16, 0, 0);
#else
  int lane = threadIdx.x & 63;
  *(us8*)(l + lane * 8) = *(const us8*)g;
#endif
}

// ---------------------------------------------------------------------------
// 1) prep: X fp32->bf16 (blocks 0..8191) ; W^T bf16 (blocks 8192..11263)
// ---------------------------------------------------------------------------
__global__ void k_prep(const float* __restrict__ X, u16* __restrict__ Xb,
                       const float* __restrict__ W0,
                       const float* __restrict__ W1,
                       const float* __restrict__ W2, u16* __restrict__ Wt) {
  int bx = blockIdx.x;
  int t = threadIdx.x;
  if (bx < 8192) {
    int idx = bx * 256 + t;
    float4 v = ((const float4*)X)[idx];
    us4v o = { f2b(v.x), f2b(v.y), f2b(v.z), f2b(v.w) };
    ((us4v*)Xb)[idx] = o;
    return;
  }
  int tb = bx - 8192;
  int mat = tb >> 10, rem = tb & 1023;
  const float* W = mat == 0 ? W0 : (mat == 1 ? W1 : W2);
  u16* dst = Wt + (size_t)mat * DM * DM;
  __shared__ float tile[32][33];
  int n0 = (rem & 31) * 32, k0 = (rem >> 5) * 32;
  int c = t & 31, r8 = t >> 5;
  for (int p = 0; p < 4; ++p) {
    int r = p * 8 + r8;
    tile[r][c] = W[(size_t)(k0 + r) * DM + n0 + c];
  }
  __syncthreads();
  for (int p = 0; p < 4; ++p) {
    int r = p * 8 + r8;
    dst[(size_t)(n0 + r) * DM + k0 + c] = f2b(tile[c][r]);
  }
}

// ---------------------------------------------------------------------------
// 2) GEMM: 128x128 tiles, BK=64, global_load_lds(16B) staging, XOR-swizzled
//    packed LDS (slot kg ^ (row&7)) -> conflict-free ds_read_b128.
//    grid=768, 2 consecutive tiles per block (same m0 -> A L2-hot; balanced,
//    3 blocks/CU all co-resident, no tail round).
//    Epilogues: mat 0/1 (Q,K) -> head-major [b][h][s][d];
//               mat 2  (V)   -> transposed [b][h][d][s] (8B vector stores).
// ---------------------------------------------------------------------------
__global__ __launch_bounds__(256) void k_gemm(
    const u16* __restrict__ Xb, const u16* __restrict__ Wt,
    const float* __restrict__ bq, const float* __restrict__ bk,
    const float* __restrict__ bv,
    u16* __restrict__ Qh, u16* __restrict__ Kh, u16* __restrict__ VtG) {
  __shared__ u16 As[128 * 64];
  __shared__ u16 Bs[128 * 64];

  int tid = threadIdx.x;
  int lane = tid & 63, wave = tid >> 6;
  int wm = wave >> 1, wn = wave & 1;
  int col = lane & 15, g = lane >> 4;

  // staging: row = wave*32 + i*8 + (lane>>3), slot = (lane&7) ^ (row&7)
  int srow = lane >> 3;
  int skg = (lane & 7) ^ srow;

  for (int tt = 0; tt < 2; ++tt) {
    int t = blockIdx.x * 2 + tt;
    int mat = t >> 9, rem = t & 511;
    int m0 = (rem >> 3) * 128, n0 = (rem & 7) * 128;
    const u16* Bw = Wt + (size_t)mat * DM * DM;
    const float* bias = mat == 0 ? bq : (mat == 1 ? bk : bv);

    const u16* gA = Xb + (size_t)(m0 + wave * 32 + srow) * DM + skg * 8;
    const u16* gB = Bw + (size_t)(n0 + wave * 32 + srow) * DM + skg * 8;

    f32x4 zero4 = {0.f, 0.f, 0.f, 0.f};
    f32x4 acc[4][4];
    for (int i = 0; i < 4; ++i)
      for (int j = 0; j < 4; ++j) acc[i][j] = zero4;

    for (int k0 = 0; k0 < DM; k0 += 64) {
#pragma unroll
      for (int i = 0; i < 4; ++i) {
        gl_lds16(gA + (size_t)i * 8 * DM + k0, &As[(wave * 32 + i * 8) * 64]);
        gl_lds16(gB + (size_t)i * 8 * DM + k0, &Bs[(wave * 32 + i * 8) * 64]);
      }
      __syncthreads();
#pragma unroll
      for (int ks = 0; ks < 2; ++ks) {
        int kg = (ks * 4 + g) ^ (col & 7);
        bf16x8 af[4], bfr[4];
#pragma unroll
        for (int mi = 0; mi < 4; ++mi)
          af[mi] = *(const bf16x8*)&As[(wm * 64 + mi * 16 + col) * 64 + kg * 8];
#pragma unroll
        for (int ni = 0; ni < 4; ++ni)
          bfr[ni] =
              *(const bf16x8*)&Bs[(wn * 64 + ni * 16 + col) * 64 + kg * 8];
#pragma unroll
        for (int mi = 0; mi < 4; ++mi)
#pragma unroll
          for (int ni = 0; ni < 4; ++ni)
            acc[mi][ni] = mfma16(af[mi], bfr[ni], acc[mi][ni]);
      }
      __syncthreads();
    }

    float bvv[4];
    for (int ni = 0; ni < 4; ++ni)
      bvv[ni] = bias[n0 + wn * 64 + ni * 16 + col];

    if (mat < 2) {
      // head-major: addr = ((b*NH + h)*SQ + s)*HD + d
      u16* C = mat == 0 ? Qh : Kh;
      for (int mi = 0; mi < 4; ++mi) {
        int m = m0 + wm * 64 + mi * 16 + g * 4;
        int bb = m >> 11, s0 = m & 2047;
        for (int r = 0; r < 4; ++r) {
          size_t base = ((size_t)(bb * NH) * SQ + (s0 + r)) * HD;
          for (int ni = 0; ni < 4; ++ni) {
            int n = n0 + wn * 64 + ni * 16 + col;
            int h = n >> 6, d = n & 63;
            C[base + (size_t)h * SQ * HD + d] = f2b(acc[mi][ni][r] + bvv[ni]);
          }
        }
      }
    } else {
      // V^T: [b][h][d][s]; rows of C are consecutive tokens s -> 8B stores
      for (int mi = 0; mi < 4; ++mi) {
        int m = m0 + wm * 64 + mi * 16 + g * 4;
        int bb = m >> 11, s0 = m & 2047;
        for (int ni = 0; ni < 4; ++ni) {
          int n = n0 + wn * 64 + ni * 16 + col;
          us4v ov = { f2b(acc[mi][ni][0] + bvv[ni]),
                      f2b(acc[mi][ni][1] + bvv[ni]),
                      f2b(acc[mi][ni][2] + bvv[ni]),
                      f2b(acc[mi][ni][3] + bvv[ni]) };
          *(us4v*)&VtG[((size_t)(bb * 1024 + n)) * SQ + s0] = ov;
        }
      }
    }
  }
}

// ---------------------------------------------------------------------------
// 3) Windowed flash attention. Block = 4 waves; each wave owns 32 queries of
//    one (b,h), loops over 5 key-chunks of 64. S^T = K*Q^T so each lane holds
//    4 consecutive keys -> vectorized P stores. All global loads line-exact
//    (Q,K head-major; V^T key-contiguous). No __syncthreads.
// ---------------------------------------------------------------------------
__global__ __launch_bounds__(256) void k_attn(
    const u16* __restrict__ Qh, const u16* __restrict__ Kh,
    const u16* __restrict__ VtG, float* __restrict__ out) {
  int bid = blockIdx.x;
  int b = bid >> 8;
  int h = (bid >> 4) & 15;
  int q0 = (bid & 15) << 7;
  int tid = threadIdx.x, lane = tid & 63, wave = tid >> 6;
  int col = lane & 15, g = lane >> 4;
  int qw = q0 + wave * 32;

  __shared__ u16 Ps[4][32 * 72];
  u16* Pw = Ps[wave];

  const u16* Qp = Qh + (size_t)(b * NH + h) * SQ * HD;
  const u16* Kp = Kh + (size_t)(b * NH + h) * SQ * HD;
  const u16* Vt = VtG + (size_t)(b * 1024 + h * 64) * SQ;

  // Q fragments (B operand: lane col = query, contiguous d)
  bf16x8 qf[2][2];
#pragma unroll
  for (int qb = 0; qb < 2; ++qb)
#pragma unroll
    for (int ks = 0; ks < 2; ++ks)
      qf[qb][ks] = *(const bf16x8*)&Qp[(size_t)(qw + qb * 16 + col) * HD +
                                       ks * 32 + g * 8];

  f32x4 zero4 = {0.f, 0.f, 0.f, 0.f};
  f32x4 o[2][4];
  float l8[2] = {0.f, 0.f};
#pragma unroll
  for (int qb = 0; qb < 2; ++qb)
#pragma unroll
    for (int nb = 0; nb < 4; ++nb) o[qb][nb] = zero4;

  const float SC = 0.18033688f;  // log2(e) / sqrt(64)
  int cbase = ((qw - 128) >> 6) << 6;

  for (int c = 0; c < 5; ++c) {
    int c0 = cbase + c * 64;
    if (c0 + 64 <= 0 || c0 >= SQ) continue;

    // S^T = K Q^T  (A = K: m = key, k = d;  B = Q: n = query)
    f32x4 s[4][2];
#pragma unroll
    for (int kb = 0; kb < 4; ++kb)
#pragma unroll
      for (int qb = 0; qb < 2; ++qb) s[kb][qb] = zero4;
#pragma unroll
    for (int ks = 0; ks < 2; ++ks) {
      bf16x8 kf[4];
#pragma unroll
      for (int kb = 0; kb < 4; ++kb) {
        int j = c0 + kb * 16 + col;
        us8 t = {0, 0, 0, 0, 0, 0, 0, 0};
        if ((unsigned)j < SQ)
          t = *(const us8*)&Kp[(size_t)j * HD + ks * 32 + g * 8];
        kf[kb] = as_bf(t);
      }
#pragma unroll
      for (int kb = 0; kb < 4; ++kb)
#pragma unroll
        for (int qb = 0; qb < 2; ++qb)
          s[kb][qb] = mfma16(kf[kb], qf[qb][ks], s[kb][qb]);
    }

    bool fullv = (c0 >= 0) && (c0 + 63 < SQ) && (c0 >= qw - 97) &&
                 (c0 + 63 <= qw + 128);
#pragma unroll
    for (int kb = 0; kb < 4; ++kb) {
#pragma unroll
      for (int qb = 0; qb < 2; ++qb) {
        float p[4];
#pragma unroll
        for (int r = 0; r < 4; ++r) {
          float e = __builtin_amdgcn_exp2f(s[kb][qb][r] * SC);
          if (!fullv) {
            int j = c0 + kb * 16 + g * 4 + r;
            int iq = qw + qb * 16 + col;
            bool ok = ((unsigned)j < SQ) && (iq - j <= WIN) && (j - iq <= WIN);
            e = ok ? e : 0.0f;
          }
          p[r] = e;
          l8[qb] += e;
        }
        union { __hip_bfloat162 h2[2]; us4v u4; } pk;
        pk.h2[0] = __float22bfloat162_rn(make_float2(p[0], p[1]));
        pk.h2[1] = __float22bfloat162_rn(make_float2(p[2], p[3]));
        *(us4v*)&Pw[(qb * 16 + col) * 72 + kb * 16 + g * 4] = pk.u4;
      }
    }

    // O += P V   (A = P: m = query, k = key; B = V^T: n = d, contiguous key)
#pragma unroll
    for (int ks = 0; ks < 2; ++ks) {
      bf16x8 pf[2], vf[4];
#pragma unroll
      for (int qb = 0; qb < 2; ++qb)
        pf[qb] = *(const bf16x8*)&Pw[(qb * 16 + col) * 72 + ks * 32 + g * 8];
      int kv = c0 + ks * 32 + g * 8;
#pragma unroll
      for (int nb = 0; nb < 4; ++nb) {
        us8 t = {0, 0, 0, 0, 0, 0, 0, 0};
        if ((unsigned)kv < SQ)
          t = *(const us8*)&Vt[(size_t)(nb * 16 + col) * SQ + kv];
        vf[nb] = as_bf(t);
      }
#pragma unroll
      for (int qb = 0; qb < 2; ++qb)
#pragma unroll
        for (int nb = 0; nb < 4; ++nb)
          o[qb][nb] = mfma16(pf[qb], vf[nb], o[qb][nb]);
    }
  }

  // denominators: lane(col,g) holds partial sum for q=col; reduce over g
#pragma unroll
  for (int qb = 0; qb < 2; ++qb) {
    l8[qb] += __shfl_xor(l8[qb], 16, 64);
    l8[qb] += __shfl_xor(l8[qb], 32, 64);
  }

#pragma unroll
  for (int qb = 0; qb < 2; ++qb)
#pragma unroll
    for (int r = 0; r < 4; ++r) {
      float inv = 1.0f / __shfl(l8[qb], g * 4 + r, 64);
      int iq = qw + qb * 16 + g * 4 + r;
      float* op = out + ((size_t)b * SQ + iq) * DM + h * HD;
#pragma unroll
      for (int nb = 0; nb < 4; ++nb) op[nb * 16 + col] = o[qb][nb][r] * inv;
    }
}

// ---------------------------------------------------------------------------
extern "C" void kernel_launch(void* const* d_in, const int* in_sizes, int n_in,
                              void* d_out, int out_size, void* d_ws,
                              size_t ws_size, hipStream_t stream) {
  const float* hs = (const float*)d_in[0];
  const float* Wq = (const float*)d_in[1];
  const float* bq = (const float*)d_in[2];
  const float* Wk = (const float*)d_in[3];
  const float* bk = (const float*)d_in[4];
  const float* Wv = (const float*)d_in[5];
  const float* bv = (const float*)d_in[6];
  float* out = (float*)d_out;
  char* ws = (char*)d_ws;

  // ws layout (bytes): Xb 16MB | Wt 6MB | Qh 16MB | Kh 16MB | Vt 16MB
  u16* Xb = (u16*)(ws);
  u16* Wt = (u16*)(ws + 16777216ULL);
  u16* Qh = (u16*)(ws + 23068672ULL);
  u16* Kh = (u16*)(ws + 39845888ULL);
  u16* Vt = (u16*)(ws + 56623104ULL);

  k_prep<<<dim3(11264), dim3(256), 0, stream>>>(hs, Xb, Wq, Wk, Wv, Wt);
  k_gemm<<<dim3(768), dim3(256), 0, stream>>>(Xb, Wt, bq, bk, bv, Qh, Kh, Vt);
  k_attn<<<dim3(1024), dim3(256), 0, stream>>>(Qh, Kh, Vt, out);
}

// Round 6
// 206.280 us; speedup vs baseline: 1.2273x; 1.2273x over previous
//
#include <hip/hip_runtime.h>
#include <hip/hip_bf16.h>

// ---------------------------------------------------------------------------
// SlidingWindowAttention: fused QKV projection (bf16 MFMA GEMM, m97-style
// global_load_lds staging, 32x32x16 compute tile) + windowed flash attention
// (bf16 MFMA, S^T trick). Q,K head-major [b][h][s][d]; V transposed
// [b][h][d][s]. fp32 output. B=4, S=2048, D=1024, H=16, hd=64, WINDOW=128.
// GEMM grid (64,24) x-fastest: consecutive blocks share B-tile (L2-friendly;
// R5 showed alternative mappings 4x the HBM fetch).
// ---------------------------------------------------------------------------

#define NB 4
#define SQ 2048
#define NH 16
#define HD 64
#define DM 1024
#define WIN 128

typedef unsigned short u16;
typedef __bf16 bf16x8 __attribute__((ext_vector_type(8)));
typedef unsigned short us8 __attribute__((ext_vector_type(8)));
typedef unsigned short us4v __attribute__((ext_vector_type(4)));
typedef float f32x4 __attribute__((ext_vector_type(4)));
typedef float f32x16 __attribute__((ext_vector_type(16)));

__device__ __forceinline__ u16 f2b(float f) {
  union { float f; unsigned u; } v; v.f = f;
  unsigned r = v.u + 0x7FFFu + ((v.u >> 16) & 1u);   // RNE
  return (u16)(r >> 16);
}

__device__ __forceinline__ bf16x8 as_bf(us8 v) {
  union { us8 a; bf16x8 b; } u; u.a = v; return u.b;
}

__device__ __forceinline__ f32x4 mfma16(bf16x8 a, bf16x8 b, f32x4 c) {
  return __builtin_amdgcn_mfma_f32_16x16x32_bf16(a, b, c, 0, 0, 0);
}
__device__ __forceinline__ f32x16 mfma32(bf16x8 a, bf16x8 b, f32x16 c) {
  return __builtin_amdgcn_mfma_f32_32x32x16_bf16(a, b, c, 0, 0, 0);
}

// async global->LDS, 16B per lane; LDS dest is wave-uniform base + lane*16
__device__ __forceinline__ void gl_lds16(const u16* g, u16* l) {
#if __has_builtin(__builtin_amdgcn_global_load_lds)
  __builtin_amdgcn_global_load_lds(
      (const __attribute__((address_space(1))) void*)g,
      (__attribute__((address_space(3))) void*)l, 16, 0, 0);
#else
  int lane = threadIdx.x & 63;
  *(us8*)(l + lane * 8) = *(const us8*)g;
#endif
}

// ---------------------------------------------------------------------------
// 1) prep: X fp32->bf16 (blocks 0..8191) ; W^T bf16 (blocks 8192..11263)
// ---------------------------------------------------------------------------
__global__ void k_prep(const float* __restrict__ X, u16* __restrict__ Xb,
                       const float* __restrict__ W0,
                       const float* __restrict__ W1,
                       const float* __restrict__ W2, u16* __restrict__ Wt) {
  int bx = blockIdx.x;
  int t = threadIdx.x;
  if (bx < 8192) {
    int idx = bx * 256 + t;
    float4 v = ((const float4*)X)[idx];
    us4v o = { f2b(v.x), f2b(v.y), f2b(v.z), f2b(v.w) };
    ((us4v*)Xb)[idx] = o;
    return;
  }
  int tb = bx - 8192;
  int mat = tb >> 10, rem = tb & 1023;
  const float* W = mat == 0 ? W0 : (mat == 1 ? W1 : W2);
  u16* dst = Wt + (size_t)mat * DM * DM;
  __shared__ float tile[32][33];
  int n0 = (rem & 31) * 32, k0 = (rem >> 5) * 32;
  int c = t & 31, r8 = t >> 5;
  for (int p = 0; p < 4; ++p) {
    int r = p * 8 + r8;
    tile[r][c] = W[(size_t)(k0 + r) * DM + n0 + c];
  }
  __syncthreads();
  for (int p = 0; p < 4; ++p) {
    int r = p * 8 + r8;
    dst[(size_t)(n0 + r) * DM + k0 + c] = f2b(tile[c][r]);
  }
}

// ---------------------------------------------------------------------------
// 2) GEMM: 128x128 tile, BK=64, global_load_lds(16B) staging, XOR-swizzled
//    packed LDS (slot = octet ^ (row&7)) -> conflict-free ds_read_b128.
//    Compute tile: 32x32x16 MFMA, wave = 64x64 as 2x2 blocks of 32x32.
//    Epilogues: mat 0/1 (Q,K) -> head-major [b][h][s][d] (64B segments);
//               mat 2  (V)   -> transposed [b][h][d][s] (8B vector stores).
// ---------------------------------------------------------------------------
__global__ __launch_bounds__(256) void k_gemm(
    const u16* __restrict__ Xb, const u16* __restrict__ Wt,
    const float* __restrict__ bq, const float* __restrict__ bk,
    const float* __restrict__ bv,
    u16* __restrict__ Qh, u16* __restrict__ Kh, u16* __restrict__ VtG) {
  int mat = blockIdx.y >> 3;
  int n0 = (blockIdx.y & 7) * 128;
  int m0 = blockIdx.x * 128;
  const u16* Bw = Wt + (size_t)mat * DM * DM;
  const float* bias = mat == 0 ? bq : (mat == 1 ? bk : bv);

  __shared__ u16 As[128 * 64];
  __shared__ u16 Bs[128 * 64];

  int tid = threadIdx.x;
  int lane = tid & 63, wave = tid >> 6;
  int wm = wave >> 1, wn = wave & 1;
  int col = lane & 31;       // m (A) / n (B) within a 32-block
  int g2 = lane >> 5;        // k-octet select

  // staging: row = wave*32 + i*8 + (lane>>3), slot = (lane&7) ^ (row&7)
  int srow = lane >> 3;
  int skg = (lane & 7) ^ srow;
  const u16* gA = Xb + (size_t)(m0 + wave * 32 + srow) * DM + skg * 8;
  const u16* gB = Bw + (size_t)(n0 + wave * 32 + srow) * DM + skg * 8;

  f32x16 acc[2][2];
#pragma unroll
  for (int i = 0; i < 2; ++i)
#pragma unroll
    for (int j = 0; j < 2; ++j)
#pragma unroll
      for (int r = 0; r < 16; ++r) acc[i][j][r] = 0.f;

  for (int k0 = 0; k0 < DM; k0 += 64) {
#pragma unroll
    for (int i = 0; i < 4; ++i) {
      gl_lds16(gA + (size_t)i * 8 * DM + k0, &As[(wave * 32 + i * 8) * 64]);
      gl_lds16(gB + (size_t)i * 8 * DM + k0, &Bs[(wave * 32 + i * 8) * 64]);
    }
    __syncthreads();
#pragma unroll
    for (int ks = 0; ks < 4; ++ks) {
      int kg = (ks * 2 + g2) ^ (col & 7);
      bf16x8 af[2], bfr[2];
#pragma unroll
      for (int mb = 0; mb < 2; ++mb)
        af[mb] = *(const bf16x8*)&As[(wm * 64 + mb * 32 + col) * 64 + kg * 8];
#pragma unroll
      for (int nb = 0; nb < 2; ++nb)
        bfr[nb] = *(const bf16x8*)&Bs[(wn * 64 + nb * 32 + col) * 64 + kg * 8];
#pragma unroll
      for (int mb = 0; mb < 2; ++mb)
#pragma unroll
        for (int nb = 0; nb < 2; ++nb)
          acc[mb][nb] = mfma32(af[mb], bfr[nb], acc[mb][nb]);
    }
    __syncthreads();
  }

  // C/D layout (32x32): col = lane&31 (n), row = (reg&3) + 8*(reg>>2) + 4*g2
  if (mat < 2) {
    // head-major: addr = ((b*NH + h)*SQ + s)*HD + d ; 32 lanes = 32 consec d
    u16* C = mat == 0 ? Qh : Kh;
#pragma unroll
    for (int mb = 0; mb < 2; ++mb) {
#pragma unroll
      for (int nb = 0; nb < 2; ++nb) {
        int n = n0 + wn * 64 + nb * 32 + col;
        int h = n >> 6, d = n & 63;
        float bb_ = bias[n];
#pragma unroll
        for (int reg = 0; reg < 16; ++reg) {
          int row = (reg & 3) + 8 * (reg >> 2) + 4 * g2;
          int m = m0 + wm * 64 + mb * 32 + row;
          int bbt = m >> 11, s = m & 2047;
          C[((size_t)(bbt * NH + h) * SQ + s) * HD + d] =
              f2b(acc[mb][nb][reg] + bb_);
        }
      }
    }
  } else {
    // V^T: [b][h][d][s]; reg quads are 4 consecutive rows (s) -> 8B stores
#pragma unroll
    for (int mb = 0; mb < 2; ++mb) {
#pragma unroll
      for (int nb = 0; nb < 2; ++nb) {
        int n = n0 + wn * 64 + nb * 32 + col;
        float bb_ = bias[n];
#pragma unroll
        for (int q = 0; q < 4; ++q) {
          int row0 = 8 * q + 4 * g2;
          int m = m0 + wm * 64 + mb * 32 + row0;
          int bbt = m >> 11, s0 = m & 2047;
          us4v ov = { f2b(acc[mb][nb][4 * q + 0] + bb_),
                      f2b(acc[mb][nb][4 * q + 1] + bb_),
                      f2b(acc[mb][nb][4 * q + 2] + bb_),
                      f2b(acc[mb][nb][4 * q + 3] + bb_) };
          *(us4v*)&VtG[((size_t)(bbt * 1024 + n)) * SQ + s0] = ov;
        }
      }
    }
  }
}

// ---------------------------------------------------------------------------
// 3) Windowed flash attention. Block = 4 waves; each wave owns 32 queries of
//    one (b,h), loops over 5 key-chunks of 64. S^T = K*Q^T so each lane holds
//    4 consecutive keys -> vectorized P stores. All global loads line-exact
//    (Q,K head-major; V^T key-contiguous). No __syncthreads.
// ---------------------------------------------------------------------------
__global__ __launch_bounds__(256) void k_attn(
    const u16* __restrict__ Qh, const u16* __restrict__ Kh,
    const u16* __restrict__ VtG, float* __restrict__ out) {
  int bid = blockIdx.x;
  int b = bid >> 8;
  int h = (bid >> 4) & 15;
  int q0 = (bid & 15) << 7;
  int tid = threadIdx.x, lane = tid & 63, wave = tid >> 6;
  int col = lane & 15, g = lane >> 4;
  int qw = q0 + wave * 32;

  __shared__ u16 Ps[4][32 * 72];
  u16* Pw = Ps[wave];

  const u16* Qp = Qh + (size_t)(b * NH + h) * SQ * HD;
  const u16* Kp = Kh + (size_t)(b * NH + h) * SQ * HD;
  const u16* Vt = VtG + (size_t)(b * 1024 + h * 64) * SQ;

  // Q fragments (B operand: lane col = query, contiguous d)
  bf16x8 qf[2][2];
#pragma unroll
  for (int qb = 0; qb < 2; ++qb)
#pragma unroll
    for (int ks = 0; ks < 2; ++ks)
      qf[qb][ks] = *(const bf16x8*)&Qp[(size_t)(qw + qb * 16 + col) * HD +
                                       ks * 32 + g * 8];

  f32x4 zero4 = {0.f, 0.f, 0.f, 0.f};
  f32x4 o[2][4];
  float l8[2] = {0.f, 0.f};
#pragma unroll
  for (int qb = 0; qb < 2; ++qb)
#pragma unroll
    for (int nb = 0; nb < 4; ++nb) o[qb][nb] = zero4;

  const float SC = 0.18033688f;  // log2(e) / sqrt(64)
  int cbase = ((qw - 128) >> 6) << 6;

  for (int c = 0; c < 5; ++c) {
    int c0 = cbase + c * 64;
    if (c0 + 64 <= 0 || c0 >= SQ) continue;

    // S^T = K Q^T  (A = K: m = key, k = d;  B = Q: n = query)
    f32x4 s[4][2];
#pragma unroll
    for (int kb = 0; kb < 4; ++kb)
#pragma unroll
      for (int qb = 0; qb < 2; ++qb) s[kb][qb] = zero4;
#pragma unroll
    for (int ks = 0; ks < 2; ++ks) {
      bf16x8 kf[4];
#pragma unroll
      for (int kb = 0; kb < 4; ++kb) {
        int j = c0 + kb * 16 + col;
        us8 t = {0, 0, 0, 0, 0, 0, 0, 0};
        if ((unsigned)j < SQ)
          t = *(const us8*)&Kp[(size_t)j * HD + ks * 32 + g * 8];
        kf[kb] = as_bf(t);
      }
#pragma unroll
      for (int kb = 0; kb < 4; ++kb)
#pragma unroll
        for (int qb = 0; qb < 2; ++qb)
          s[kb][qb] = mfma16(kf[kb], qf[qb][ks], s[kb][qb]);
    }

    bool fullv = (c0 >= 0) && (c0 + 63 < SQ) && (c0 >= qw - 97) &&
                 (c0 + 63 <= qw + 128);
#pragma unroll
    for (int kb = 0; kb < 4; ++kb) {
#pragma unroll
      for (int qb = 0; qb < 2; ++qb) {
        float p[4];
#pragma unroll
        for (int r = 0; r < 4; ++r) {
          float e = __builtin_amdgcn_exp2f(s[kb][qb][r] * SC);
          if (!fullv) {
            int j = c0 + kb * 16 + g * 4 + r;
            int iq = qw + qb * 16 + col;
            bool ok = ((unsigned)j < SQ) && (iq - j <= WIN) && (j - iq <= WIN);
            e = ok ? e : 0.0f;
          }
          p[r] = e;
          l8[qb] += e;
        }
        union { __hip_bfloat162 h2[2]; us4v u4; } pk;
        pk.h2[0] = __float22bfloat162_rn(make_float2(p[0], p[1]));
        pk.h2[1] = __float22bfloat162_rn(make_float2(p[2], p[3]));
        *(us4v*)&Pw[(qb * 16 + col) * 72 + kb * 16 + g * 4] = pk.u4;
      }
    }

    // O += P V   (A = P: m = query, k = key; B = V^T: n = d, contiguous key)
#pragma unroll
    for (int ks = 0; ks < 2; ++ks) {
      bf16x8 pf[2], vf[4];
#pragma unroll
      for (int qb = 0; qb < 2; ++qb)
        pf[qb] = *(const bf16x8*)&Pw[(qb * 16 + col) * 72 + ks * 32 + g * 8];
      int kv = c0 + ks * 32 + g * 8;
#pragma unroll
      for (int nb = 0; nb < 4; ++nb) {
        us8 t = {0, 0, 0, 0, 0, 0, 0, 0};
        if ((unsigned)kv < SQ)
          t = *(const us8*)&Vt[(size_t)(nb * 16 + col) * SQ + kv];
        vf[nb] = as_bf(t);
      }
#pragma unroll
      for (int qb = 0; qb < 2; ++qb)
#pragma unroll
        for (int nb = 0; nb < 4; ++nb)
          o[qb][nb] = mfma16(pf[qb], vf[nb], o[qb][nb]);
    }
  }

  // denominators: lane(col,g) holds partial sum for q=col; reduce over g
#pragma unroll
  for (int qb = 0; qb < 2; ++qb) {
    l8[qb] += __shfl_xor(l8[qb], 16, 64);
    l8[qb] += __shfl_xor(l8[qb], 32, 64);
  }

#pragma unroll
  for (int qb = 0; qb < 2; ++qb)
#pragma unroll
    for (int r = 0; r < 4; ++r) {
      float inv = 1.0f / __shfl(l8[qb], g * 4 + r, 64);
      int iq = qw + qb * 16 + g * 4 + r;
      float* op = out + ((size_t)b * SQ + iq) * DM + h * HD;
#pragma unroll
      for (int nb = 0; nb < 4; ++nb) op[nb * 16 + col] = o[qb][nb][r] * inv;
    }
}

// ---------------------------------------------------------------------------
extern "C" void kernel_launch(void* const* d_in, const int* in_sizes, int n_in,
                              void* d_out, int out_size, void* d_ws,
                              size_t ws_size, hipStream_t stream) {
  const float* hs = (const float*)d_in[0];
  const float* Wq = (const float*)d_in[1];
  const float* bq = (const float*)d_in[2];
  const float* Wk = (const float*)d_in[3];
  const float* bk = (const float*)d_in[4];
  const float* Wv = (const float*)d_in[5];
  const float* bv = (const float*)d_in[6];
  float* out = (float*)d_out;
  char* ws = (char*)d_ws;

  // ws layout (bytes): Xb 16MB | Wt 6MB | Qh 16MB | Kh 16MB | Vt 16MB
  u16* Xb = (u16*)(ws);
  u16* Wt = (u16*)(ws + 16777216ULL);
  u16* Qh = (u16*)(ws + 23068672ULL);
  u16* Kh = (u16*)(ws + 39845888ULL);
  u16* Vt = (u16*)(ws + 56623104ULL);

  k_prep<<<dim3(11264), dim3(256), 0, stream>>>(hs, Xb, Wq, Wk, Wv, Wt);
  k_gemm<<<dim3(64, 24), dim3(256), 0, stream>>>(Xb, Wt, bq, bk, bv, Qh, Kh, Vt);
  k_attn<<<dim3(1024), dim3(256), 0, stream>>>(Qh, Kh, Vt, out);
}